// Round 10
// baseline (51.043 us; speedup 1.0000x reference)
//
#include <hip/hip_runtime.h>
#include <math.h>

#define MM 512
#define NN 1024
#define BB 64
#define SS 50
#define ETA 0.1f
#define AGENT __HIP_MEMORY_SCOPE_AGENT

// k_pipe grid: [0,256) h1z | [256,512) c | [512,576) sm
#define P_C0 256
#define P_S0 512
#define NPIPE 576

__device__ __forceinline__ float aload(const float* p) {
  return __hip_atomic_load(p, __ATOMIC_RELAXED, AGENT);
}
// RMW store: executes at the MALL (coherence point). After vmcnt(0) drains
// (implicit in __syncthreads), the data is GLOBALLY visible — unlike a plain
// relaxed store, whose write-through is posted (r9 race root cause).
__device__ __forceinline__ void xstore(float* p, float v) {
  (void)__hip_atomic_exchange(p, v, __ATOMIC_RELAXED, AGENT);
}
__device__ __forceinline__ void bump(unsigned* p) {
  __hip_atomic_fetch_add(p, 1u, __ATOMIC_RELAXED, AGENT);
}
__device__ __forceinline__ void spin_ge(const unsigned* p, unsigned tgt) {
  while (__hip_atomic_load(p, __ATOMIC_RELAXED, AGENT) < tgt)
    __builtin_amdgcn_s_sleep(2);
}

// K1: R_t[b][m] = Y[b,m] - sum_n A[m,n]*X[n,b]   (r8-proven)
// grid 256, block (64,8). Block 0 additionally zeroes the 96 pipe counters;
// the dispatch boundary makes them coherent for k_pipe.
__global__ __launch_bounds__(512) void k_r(const float* __restrict__ X,
                                           const float* __restrict__ Y,
                                           const float* __restrict__ A,
                                           float* __restrict__ R_t,
                                           unsigned* __restrict__ cnt) {
  const int l = threadIdx.x;          // batch b
  const int w = threadIdx.y;          // n-chunk 0..7
  const int m0 = blockIdx.x * 2;
  if (blockIdx.x == 0) {
    const int tid = w * 64 + l;
    if (tid < 96) __hip_atomic_store(&cnt[tid], 0u, __ATOMIC_RELAXED, AGENT);
  }
  __shared__ float part[8][2][BB];
  const float* __restrict__ Xp = X + w * 128 * BB + l;
  const float* __restrict__ A0 = A + (size_t)m0 * NN + w * 128;
  const float* __restrict__ A1 = A0 + NN;
  float r0a = 0.f, r0b = 0.f, r1a = 0.f, r1b = 0.f;
  #pragma unroll 8
  for (int i = 0; i < 128; i += 4) {
    const float x0 = Xp[(i + 0) * BB];
    const float x1 = Xp[(i + 1) * BB];
    const float x2 = Xp[(i + 2) * BB];
    const float x3 = Xp[(i + 3) * BB];
    const float4 a0 = *reinterpret_cast<const float4*>(A0 + i);
    const float4 a1 = *reinterpret_cast<const float4*>(A1 + i);
    r0a = fmaf(a0.x, x0, fmaf(a0.y, x1, r0a));
    r0b = fmaf(a0.z, x2, fmaf(a0.w, x3, r0b));
    r1a = fmaf(a1.x, x0, fmaf(a1.y, x1, r1a));
    r1b = fmaf(a1.z, x2, fmaf(a1.w, x3, r1b));
  }
  part[w][0][l] = r0a + r0b;
  part[w][1][l] = r1a + r1b;
  __syncthreads();
  if (w == 0) {
    const float s0 =
        ((part[0][0][l] + part[1][0][l]) + (part[2][0][l] + part[3][0][l])) +
        ((part[4][0][l] + part[5][0][l]) + (part[6][0][l] + part[7][0][l]));
    const float s1 =
        ((part[0][1][l] + part[1][1][l]) + (part[2][1][l] + part[3][1][l])) +
        ((part[4][1][l] + part[5][1][l]) + (part[6][1][l] + part[7][1][l]));
    const float2 y2 = *reinterpret_cast<const float2*>(Y + l * MM + m0);
    *reinterpret_cast<float2*>(R_t + l * MM + m0) =
        make_float2(y2.x - s0, y2.y - s1);
  }
}

// K2: dataflow pipeline, one dispatch: h1z -> c -> sm via counter spins.
// LDS union 40KB -> 4 blocks/CU; launch_bounds(512,6) -> >=3 blocks/CU
// -> >=768 co-resident >= 576: deadlock-free in any dispatch order.
__global__ __launch_bounds__(512, 6) void k_pipe(
    const float* __restrict__ X,   // (N,B)
    const float* __restrict__ A,   // (M,N)
    const float* __restrict__ R_t, // (B,M) from k_r (dispatch-coherent)
    const float* __restrict__ W,   // (N)
    float* __restrict__ z_t,       // (B,N) ws
    float* __restrict__ H1_t,      // (B,N) ws
    float* __restrict__ c_part,    // (B,4,N) ws
    unsigned* __restrict__ cnt,    // 96: [0,32) cnt_h, [32,96) cnt_c
    float* __restrict__ out) {     // (N,B)
  __shared__ __align__(16) char smem[40960];
  const int bid = blockIdx.x;
  const int t = threadIdx.x;  // 0..511
  const int l = t & 63;
  const int w = t >> 6;
  unsigned* cnt_h = cnt;       // [32] -> 8 bumps each
  unsigned* cnt_c = cnt + 32;  // [64] -> 4 bumps each

  if (bid < P_C0) {
    // ===== h1z: H1_t[b,n], z_t[b,n] (R ready at kernel start) =====
    const int nc = bid & 7;   // n-chunk of 128
    const int bp = bid >> 3;  // b-pair
    float* Rs = reinterpret_cast<float*>(smem);                            // 4KB
    float(*p2)[4][128] = reinterpret_cast<float(*)[4][128]>(smem + 4096);  // 4KB
    Rs[t] = R_t[(size_t)(bp * 2) * MM + t];
    Rs[512 + t] = R_t[(size_t)(bp * 2 + 1) * MM + t];
    __syncthreads();
    const int b_l = w >> 2;  // 0..1
    const int mc = w & 3;    // m-chunk of 128
    const int n0 = nc * 128;
    const float2* __restrict__ A2 =
        reinterpret_cast<const float2*>(A) + (size_t)(mc * 128) * (NN / 2) + n0 / 2 + l;
    const float4* __restrict__ R4 =
        reinterpret_cast<const float4*>(Rs + b_l * MM) + mc * 32;
    float s0 = 0.f, s1 = 0.f, s2 = 0.f, s3 = 0.f;
    float u0 = 0.f, u1 = 0.f, u2 = 0.f, u3 = 0.f;
    #pragma unroll 2
    for (int i = 0; i < 128; i += 4) {
      const float4 r = R4[i >> 2];
      const float2 q0 = A2[(size_t)(i + 0) * (NN / 2)];
      const float2 q1 = A2[(size_t)(i + 1) * (NN / 2)];
      const float2 q2 = A2[(size_t)(i + 2) * (NN / 2)];
      const float2 q3 = A2[(size_t)(i + 3) * (NN / 2)];
      s0 = fmaf(q0.x, r.x, s0); u0 = fmaf(q0.y, r.x, u0);
      s1 = fmaf(q1.x, r.y, s1); u1 = fmaf(q1.y, r.y, u1);
      s2 = fmaf(q2.x, r.z, s2); u2 = fmaf(q2.y, r.z, u2);
      s3 = fmaf(q3.x, r.w, s3); u3 = fmaf(q3.y, r.w, u3);
    }
    p2[b_l][mc][l * 2 + 0] = (s0 + s1) + (s2 + s3);
    p2[b_l][mc][l * 2 + 1] = (u0 + u1) + (u2 + u3);
    __syncthreads();
    if (t < 256) {
      const int bl2 = t >> 7;
      const int nn = t & 127;
      const int bb = bp * 2 + bl2;
      const int n = n0 + nn;
      const float s = (p2[bl2][0][nn] + p2[bl2][1][nn]) +
                      (p2[bl2][2][nn] + p2[bl2][3][nn]);
      const float h = fmaf(ETA, s, X[n * BB + bb]);
      xstore(&H1_t[bb * NN + n], h);
      xstore(&z_t[bb * NN + n], fabsf(W[n] * h));
    }
    __syncthreads();  // per-wave vmcnt(0): exchanges acked at MALL
    if (t == 0) bump(&cnt_h[bp]);

  } else if (bid < P_S0) {
    // ===== c: c_part[b][q][n], q-chunk of 256 j =====
    const int local = bid - P_C0;
    const int b = local >> 2;
    const int q = local & 3;
    if (t == 0) spin_ge(&cnt_h[b >> 1], 8u);
    __syncthreads();
    float* zsf = reinterpret_cast<float*>(smem);  // 4KB
    zsf[t] = aload(&z_t[b * NN + t]);
    zsf[t + 512] = aload(&z_t[b * NN + t + 512]);
    __syncthreads();
    const float zn0 = zsf[t];
    const float zn1 = zsf[t + 512];
    float c0 = 0.f, c1 = 0.f;
    const float4* zq = reinterpret_cast<const float4*>(zsf) + q * 64;
    #pragma unroll 4
    for (int i = 0; i < 64; ++i) {
      const float4 f = zq[i];
      c0 += (fabsf(zn0 - f.x) + fabsf(zn0 - f.y)) +
            (fabsf(zn0 - f.z) + fabsf(zn0 - f.w));
      c1 += (fabsf(zn1 - f.x) + fabsf(zn1 - f.y)) +
            (fabsf(zn1 - f.z) + fabsf(zn1 - f.w));
    }
    float* cp = c_part + (size_t)(b * 4 + q) * NN;
    xstore(cp + t, c0);
    xstore(cp + t + 512, c1);
    __syncthreads();
    if (t == 0) bump(&cnt_c[b]);

  } else {
    // ===== sm: softmax + mask + out =====
    const int b = bid - P_S0;
    if (t == 0) {
      spin_ge(&cnt_h[b >> 1], 8u);  // z/H1 visible (also implied by cnt_c)
      spin_ge(&cnt_c[b], 4u);
    }
    __syncthreads();
    float2* zc = reinterpret_cast<float2*>(smem);                          // 8KB
    float(*mpart)[NN] = reinterpret_cast<float(*)[NN]>(smem + 8192);       // 32KB
    const float* __restrict__ cb = c_part + (size_t)b * 4 * NN;
    {
      const int i0 = t, i1 = t + 512;
      const float cA = (aload(cb + i0) + aload(cb + i0 + NN)) +
                       (aload(cb + i0 + 2 * NN) + aload(cb + i0 + 3 * NN));
      const float cB = (aload(cb + i1) + aload(cb + i1 + NN)) +
                       (aload(cb + i1 + 2 * NN) + aload(cb + i1 + 3 * NN));
      zc[i0] = make_float2(aload(&z_t[b * NN + i0]), cA);
      zc[i1] = make_float2(aload(&z_t[b * NN + i1]), cB);
    }
    const float h0 = aload(&H1_t[b * NN + t]);
    const float h1 = aload(&H1_t[b * NN + t + 512]);
    __syncthreads();

    float zz[16], cc[16], mp[16];
    #pragma unroll
    for (int k = 0; k < 16; ++k) {
      const float2 v = zc[l + 64 * k];
      zz[k] = v.x;
      cc[k] = v.y;
      mp[k] = 0.f;
    }
    for (int s = w; s < SS; s += 8) {
      const float ks = (float)(NN + 1 - 2 * (s + 1));
      float lg[16];
      float mx = -INFINITY;
      #pragma unroll
      for (int k = 0; k < 16; ++k) {
        lg[k] = fmaf(ks, zz[k], -cc[k]);
        mx = fmaxf(mx, lg[k]);
      }
      #pragma unroll
      for (int off = 32; off > 0; off >>= 1)
        mx = fmaxf(mx, __shfl_xor(mx, off, 64));
      float sum = 0.f;
      #pragma unroll
      for (int k = 0; k < 16; ++k) {
        lg[k] = __expf(lg[k] - mx);
        sum += lg[k];
      }
      #pragma unroll
      for (int off = 32; off > 0; off >>= 1)
        sum += __shfl_xor(sum, off, 64);
      const float rs = 1.f / sum;
      #pragma unroll
      for (int k = 0; k < 16; ++k) mp[k] = fmaf(lg[k], rs, mp[k]);
    }
    #pragma unroll
    for (int k = 0; k < 16; ++k) mpart[w][l + 64 * k] = mp[k];
    __syncthreads();

    float m0 = 0.f, m1 = 0.f;
    #pragma unroll
    for (int u = 0; u < 8; ++u) {
      m0 += mpart[u][t];
      m1 += mpart[u][t + 512];
    }
    out[t * BB + b] = m0 * h0;
    out[(t + 512) * BB + b] = m1 * h1;
  }
}

extern "C" void kernel_launch(void* const* d_in, const int* in_sizes, int n_in,
                              void* d_out, int out_size, void* d_ws, size_t ws_size,
                              hipStream_t stream) {
  const float* X = (const float*)d_in[0];  // (N,B)
  const float* Y = (const float*)d_in[1];  // (B,M)
  const float* A = (const float*)d_in[2];  // (M,N)
  const float* W = (const float*)d_in[3];  // (N,)
  float* out = (float*)d_out;              // (N,B)

  float* R_t = (float*)d_ws;               // 32768 f
  float* z_t = R_t + BB * MM;              // 65536 f
  float* H1_t = z_t + BB * NN;             // 65536 f
  float* c_part = H1_t + BB * NN;          // 262144 f
  unsigned* cnt = (unsigned*)(c_part + 4 * BB * NN);  // 96 u32

  k_r   <<<dim3(MM / 2), dim3(64, 8), 0, stream>>>(X, Y, A, R_t, cnt);
  k_pipe<<<dim3(NPIPE), dim3(512), 0, stream>>>(X, A, R_t, W, z_t, H1_t,
                                                c_part, cnt, out);
}

// Round 11
// 38.368 us; speedup vs baseline: 1.3303x; 1.3303x over previous
//
#include <hip/hip_runtime.h>
#include <math.h>

#define MM 512
#define NN 1024
#define BB 64
#define SS 50
#define ETA 0.1f

// K1: R_t[b][m] = Y[b,m] - sum_n A[m,n]*X[n,b]   (r8-proven)
// grid 256, block (64,8). Block owns 2 m-rows; wave w sums n-chunk w (128 n);
// 8-way LDS tree reduce; wave 0 writes float2 (m-pair) per batch.
__global__ __launch_bounds__(512) void k_r(const float* __restrict__ X,
                                           const float* __restrict__ Y,
                                           const float* __restrict__ A,
                                           float* __restrict__ R_t) {
  const int l = threadIdx.x;          // batch b
  const int w = threadIdx.y;          // n-chunk 0..7
  const int m0 = blockIdx.x * 2;
  __shared__ float part[8][2][BB];
  const float* __restrict__ Xp = X + w * 128 * BB + l;
  const float* __restrict__ A0 = A + (size_t)m0 * NN + w * 128;
  const float* __restrict__ A1 = A0 + NN;
  float r0a = 0.f, r0b = 0.f, r1a = 0.f, r1b = 0.f;
  #pragma unroll 8
  for (int i = 0; i < 128; i += 4) {
    const float x0 = Xp[(i + 0) * BB];
    const float x1 = Xp[(i + 1) * BB];
    const float x2 = Xp[(i + 2) * BB];
    const float x3 = Xp[(i + 3) * BB];
    const float4 a0 = *reinterpret_cast<const float4*>(A0 + i);
    const float4 a1 = *reinterpret_cast<const float4*>(A1 + i);
    r0a = fmaf(a0.x, x0, fmaf(a0.y, x1, r0a));
    r0b = fmaf(a0.z, x2, fmaf(a0.w, x3, r0b));
    r1a = fmaf(a1.x, x0, fmaf(a1.y, x1, r1a));
    r1b = fmaf(a1.z, x2, fmaf(a1.w, x3, r1b));
  }
  part[w][0][l] = r0a + r0b;
  part[w][1][l] = r1a + r1b;
  __syncthreads();
  if (w == 0) {
    const float s0 =
        ((part[0][0][l] + part[1][0][l]) + (part[2][0][l] + part[3][0][l])) +
        ((part[4][0][l] + part[5][0][l]) + (part[6][0][l] + part[7][0][l]));
    const float s1 =
        ((part[0][1][l] + part[1][1][l]) + (part[2][1][l] + part[3][1][l])) +
        ((part[4][1][l] + part[5][1][l]) + (part[6][1][l] + part[7][1][l]));
    const float2 y2 = *reinterpret_cast<const float2*>(Y + l * MM + m0);
    *reinterpret_cast<float2*>(R_t + l * MM + m0) =
        make_float2(y2.x - s0, y2.y - s1);
  }
}

// K2: H1_t[b,n] = X[n,b] + ETA*sum_m A[m,n]*R[m,b]; z_t[b,n] = |W[n]*H1|.
// grid 256 (8 nc x 32 bp), block (64,8). R staged in LDS; unroll 4.
__global__ __launch_bounds__(512) void k_h1z(const float* __restrict__ X,
                                             const float* __restrict__ A,
                                             const float* __restrict__ R_t,
                                             const float* __restrict__ W,
                                             float* __restrict__ H1_t,
                                             float* __restrict__ z_t) {
  const int l = threadIdx.x;
  const int w = threadIdx.y;          // 0..7
  const int nc = blockIdx.x & 7;
  const int bp = blockIdx.x >> 3;     // 0..31
  const int t5 = w * 64 + l;          // 0..511
  __shared__ __align__(16) float Rs[2][MM];
  __shared__ float p2[2][4][128];

  if (t5 < 256) {
    const int row = t5 >> 7;          // 0..1
    const int idx = t5 & 127;         // 0..127 float4s
    reinterpret_cast<float4*>(Rs[row])[idx] =
        reinterpret_cast<const float4*>(R_t + (size_t)(bp * 2 + row) * MM)[idx];
  }
  __syncthreads();

  const int b_l = w >> 2;             // 0..1
  const int mc = w & 3;               // m-chunk of 128
  const int n0 = nc * 128;
  const float2* __restrict__ A2 =
      reinterpret_cast<const float2*>(A) + (size_t)(mc * 128) * (NN / 2) + n0 / 2 + l;
  const float4* __restrict__ R4 =
      reinterpret_cast<const float4*>(Rs[b_l]) + mc * 32;
  float s0 = 0.f, s1 = 0.f, s2 = 0.f, s3 = 0.f;
  float u0 = 0.f, u1 = 0.f, u2 = 0.f, u3 = 0.f;
  #pragma unroll 4
  for (int i = 0; i < 128; i += 4) {
    const float4 r = R4[i >> 2];
    const float2 q0 = A2[(size_t)(i + 0) * (NN / 2)];
    const float2 q1 = A2[(size_t)(i + 1) * (NN / 2)];
    const float2 q2 = A2[(size_t)(i + 2) * (NN / 2)];
    const float2 q3 = A2[(size_t)(i + 3) * (NN / 2)];
    s0 = fmaf(q0.x, r.x, s0); u0 = fmaf(q0.y, r.x, u0);
    s1 = fmaf(q1.x, r.y, s1); u1 = fmaf(q1.y, r.y, u1);
    s2 = fmaf(q2.x, r.z, s2); u2 = fmaf(q2.y, r.z, u2);
    s3 = fmaf(q3.x, r.w, s3); u3 = fmaf(q3.y, r.w, u3);
  }
  p2[b_l][mc][l * 2 + 0] = (s0 + s1) + (s2 + s3);
  p2[b_l][mc][l * 2 + 1] = (u0 + u1) + (u2 + u3);
  __syncthreads();
  if (t5 < 256) {
    const int bl2 = t5 >> 7;
    const int nn = t5 & 127;
    const int bb = bp * 2 + bl2;
    const int n = n0 + nn;
    const float s = (p2[bl2][0][nn] + p2[bl2][1][nn]) +
                    (p2[bl2][2][nn] + p2[bl2][3][nn]);
    const float h = fmaf(ETA, s, X[n * BB + bb]);
    H1_t[bb * NN + n] = h;
    z_t[bb * NN + n] = fabsf(W[n] * h);
  }
}

// K3: sort-based c + softmax + out. grid 64 (block = batch), 1024 threads.
// c[n] = sum_j |z_n - z_j| = (2r+2-N)*z_(r) + S - 2*P_r  for z sorted asc,
// rank r, inclusive prefix P_r, total S (exact identity). Bitonic sort:
// thread owns slot t; 45/55 stages intra-wave (shfl, no sync), 10 cross-wave
// (LDS, 2 syncs each). Then r8's verified 16-wave softmax.
__global__ __launch_bounds__(1024) void k_smc(const float* __restrict__ z_t,
                                              const float* __restrict__ H1_t,
                                              float* __restrict__ out) {
  const int b = blockIdx.x;
  const int t = threadIdx.x;  // 0..1023 = slot
  const int l = t & 63;
  const int w = t >> 6;
  __shared__ float zs[NN];       // z by original n (softmax input)
  __shared__ float sv[NN];       // sort scratch -> reused as c by n
  __shared__ int si[NN];         // sort scratch (indices)
  __shared__ float wsum[16];
  __shared__ float mpart[16][NN];

  const float zval = z_t[b * NN + t];
  const float h = H1_t[b * NN + t];
  zs[t] = zval;

  // ---- bitonic sort of (v, idx), ascending lex ----
  float v = zval;
  int idx = t;
  for (int k = 2; k <= NN; k <<= 1) {
    for (int j = k >> 1; j > 0; j >>= 1) {
      float pv;
      int pi;
      if (j >= 64) {
        __syncthreads();
        sv[t] = v;
        si[t] = idx;
        __syncthreads();
        pv = sv[t ^ j];
        pi = si[t ^ j];
      } else {
        pv = __shfl_xor(v, j, 64);
        pi = __shfl_xor(idx, j, 64);
      }
      const bool want_min = (((t & j) == 0) == ((t & k) == 0));
      const bool mine_less = (v < pv) || (v == pv && idx < pi);
      if (want_min != mine_less) {
        v = pv;
        idx = pi;
      }
    }
  }

  // ---- inclusive prefix P_t of sorted v; total S ----
  float p = v;
  #pragma unroll
  for (int d = 1; d < 64; d <<= 1) {
    const float pu = __shfl_up(p, d, 64);
    if (l >= d) p += pu;
  }
  if (l == 63) wsum[w] = p;
  __syncthreads();
  float off = 0.f, S = 0.f;
  #pragma unroll
  for (int u = 0; u < 16; ++u) {
    const float ws = wsum[u];
    if (u < w) off += ws;
    S += ws;
  }
  const float P = p + off;
  const float c = fmaf((float)(2 * t + 2 - NN), v, S - 2.f * P);
  // scatter c back to original-n order (sv reused; idx is a permutation)
  sv[idx] = c;
  __syncthreads();

  // ---- softmax + mask (wave w: s = w, w+16, w+32, (w+48)) ----
  float zz[16], cc[16], mp[16];
  #pragma unroll
  for (int k = 0; k < 16; ++k) {
    zz[k] = zs[l + 64 * k];
    cc[k] = sv[l + 64 * k];
    mp[k] = 0.f;
  }
  for (int s = w; s < SS; s += 16) {
    const float ks = (float)(NN + 1 - 2 * (s + 1));
    float lg[16];
    float mx = -INFINITY;
    #pragma unroll
    for (int k = 0; k < 16; ++k) {
      lg[k] = fmaf(ks, zz[k], -cc[k]);
      mx = fmaxf(mx, lg[k]);
    }
    #pragma unroll
    for (int off2 = 32; off2 > 0; off2 >>= 1)
      mx = fmaxf(mx, __shfl_xor(mx, off2, 64));
    float sum = 0.f;
    #pragma unroll
    for (int k = 0; k < 16; ++k) {
      lg[k] = __expf(lg[k] - mx);
      sum += lg[k];
    }
    #pragma unroll
    for (int off2 = 32; off2 > 0; off2 >>= 1)
      sum += __shfl_xor(sum, off2, 64);
    const float rs = 1.f / sum;
    #pragma unroll
    for (int k = 0; k < 16; ++k) mp[k] = fmaf(lg[k], rs, mp[k]);
  }
  #pragma unroll
  for (int k = 0; k < 16; ++k) mpart[w][l + 64 * k] = mp[k];
  __syncthreads();

  float mask = 0.f;
  #pragma unroll
  for (int u = 0; u < 16; ++u) mask += mpart[u][t];
  out[t * BB + b] = mask * h;
}

extern "C" void kernel_launch(void* const* d_in, const int* in_sizes, int n_in,
                              void* d_out, int out_size, void* d_ws, size_t ws_size,
                              hipStream_t stream) {
  const float* X = (const float*)d_in[0];  // (N,B)
  const float* Y = (const float*)d_in[1];  // (B,M)
  const float* A = (const float*)d_in[2];  // (M,N)
  const float* W = (const float*)d_in[3];  // (N,)
  float* out = (float*)d_out;              // (N,B)

  float* R_t = (float*)d_ws;               // (B,M) = 32768 f
  float* z_t = R_t + BB * MM;              // (B,N) = 65536 f
  float* H1_t = z_t + BB * NN;             // (B,N) = 65536 f

  k_r   <<<dim3(MM / 2), dim3(64, 8), 0, stream>>>(X, Y, A, R_t);
  k_h1z <<<dim3(256), dim3(64, 8), 0, stream>>>(X, A, R_t, W, H1_t, z_t);
  k_smc <<<dim3(BB), dim3(1024), 0, stream>>>(z_t, H1_t, out);
}

// Round 12
// 36.879 us; speedup vs baseline: 1.3841x; 1.0404x over previous
//
#include <hip/hip_runtime.h>
#include <math.h>

#define MM 512
#define NN 1024
#define BB 64
#define SS 50
#define ETA 0.1f

// K1: R_t[b][m] = Y[b,m] - sum_n A[m,n]*X[n,b]   (r8-proven)
// grid 256, block (64,8). Block owns 2 m-rows; wave w sums n-chunk w (128 n);
// 8-way LDS tree reduce; wave 0 writes float2 (m-pair) per batch.
__global__ __launch_bounds__(512) void k_r(const float* __restrict__ X,
                                           const float* __restrict__ Y,
                                           const float* __restrict__ A,
                                           float* __restrict__ R_t) {
  const int l = threadIdx.x;          // batch b
  const int w = threadIdx.y;          // n-chunk 0..7
  const int m0 = blockIdx.x * 2;
  __shared__ float part[8][2][BB];
  const float* __restrict__ Xp = X + w * 128 * BB + l;
  const float* __restrict__ A0 = A + (size_t)m0 * NN + w * 128;
  const float* __restrict__ A1 = A0 + NN;
  float r0a = 0.f, r0b = 0.f, r1a = 0.f, r1b = 0.f;
  #pragma unroll 8
  for (int i = 0; i < 128; i += 4) {
    const float x0 = Xp[(i + 0) * BB];
    const float x1 = Xp[(i + 1) * BB];
    const float x2 = Xp[(i + 2) * BB];
    const float x3 = Xp[(i + 3) * BB];
    const float4 a0 = *reinterpret_cast<const float4*>(A0 + i);
    const float4 a1 = *reinterpret_cast<const float4*>(A1 + i);
    r0a = fmaf(a0.x, x0, fmaf(a0.y, x1, r0a));
    r0b = fmaf(a0.z, x2, fmaf(a0.w, x3, r0b));
    r1a = fmaf(a1.x, x0, fmaf(a1.y, x1, r1a));
    r1b = fmaf(a1.z, x2, fmaf(a1.w, x3, r1b));
  }
  part[w][0][l] = r0a + r0b;
  part[w][1][l] = r1a + r1b;
  __syncthreads();
  if (w == 0) {
    const float s0 =
        ((part[0][0][l] + part[1][0][l]) + (part[2][0][l] + part[3][0][l])) +
        ((part[4][0][l] + part[5][0][l]) + (part[6][0][l] + part[7][0][l]));
    const float s1 =
        ((part[0][1][l] + part[1][1][l]) + (part[2][1][l] + part[3][1][l])) +
        ((part[4][1][l] + part[5][1][l]) + (part[6][1][l] + part[7][1][l]));
    const float2 y2 = *reinterpret_cast<const float2*>(Y + l * MM + m0);
    *reinterpret_cast<float2*>(R_t + l * MM + m0) =
        make_float2(y2.x - s0, y2.y - s1);
  }
}

// K2: H1_t[b,n] = X[n,b] + ETA*sum_m A[m,n]*R[m,b]; z_t[b,n] = |W[n]*H1|.
// grid 256 (8 nc x 32 bp), block (64,8). R staged in LDS; unroll 4.
__global__ __launch_bounds__(512) void k_h1z(const float* __restrict__ X,
                                             const float* __restrict__ A,
                                             const float* __restrict__ R_t,
                                             const float* __restrict__ W,
                                             float* __restrict__ H1_t,
                                             float* __restrict__ z_t) {
  const int l = threadIdx.x;
  const int w = threadIdx.y;          // 0..7
  const int nc = blockIdx.x & 7;
  const int bp = blockIdx.x >> 3;     // 0..31
  const int t5 = w * 64 + l;          // 0..511
  __shared__ __align__(16) float Rs[2][MM];
  __shared__ float p2[2][4][128];

  if (t5 < 256) {
    const int row = t5 >> 7;          // 0..1
    const int idx = t5 & 127;         // 0..127 float4s
    reinterpret_cast<float4*>(Rs[row])[idx] =
        reinterpret_cast<const float4*>(R_t + (size_t)(bp * 2 + row) * MM)[idx];
  }
  __syncthreads();

  const int b_l = w >> 2;             // 0..1
  const int mc = w & 3;               // m-chunk of 128
  const int n0 = nc * 128;
  const float2* __restrict__ A2 =
      reinterpret_cast<const float2*>(A) + (size_t)(mc * 128) * (NN / 2) + n0 / 2 + l;
  const float4* __restrict__ R4 =
      reinterpret_cast<const float4*>(Rs[b_l]) + mc * 32;
  float s0 = 0.f, s1 = 0.f, s2 = 0.f, s3 = 0.f;
  float u0 = 0.f, u1 = 0.f, u2 = 0.f, u3 = 0.f;
  #pragma unroll 4
  for (int i = 0; i < 128; i += 4) {
    const float4 r = R4[i >> 2];
    const float2 q0 = A2[(size_t)(i + 0) * (NN / 2)];
    const float2 q1 = A2[(size_t)(i + 1) * (NN / 2)];
    const float2 q2 = A2[(size_t)(i + 2) * (NN / 2)];
    const float2 q3 = A2[(size_t)(i + 3) * (NN / 2)];
    s0 = fmaf(q0.x, r.x, s0); u0 = fmaf(q0.y, r.x, u0);
    s1 = fmaf(q1.x, r.y, s1); u1 = fmaf(q1.y, r.y, u1);
    s2 = fmaf(q2.x, r.z, s2); u2 = fmaf(q2.y, r.z, u2);
    s3 = fmaf(q3.x, r.w, s3); u3 = fmaf(q3.y, r.w, u3);
  }
  p2[b_l][mc][l * 2 + 0] = (s0 + s1) + (s2 + s3);
  p2[b_l][mc][l * 2 + 1] = (u0 + u1) + (u2 + u3);
  __syncthreads();
  if (t5 < 256) {
    const int bl2 = t5 >> 7;
    const int nn = t5 & 127;
    const int bb = bp * 2 + bl2;
    const int n = n0 + nn;
    const float s = (p2[bl2][0][nn] + p2[bl2][1][nn]) +
                    (p2[bl2][2][nn] + p2[bl2][3][nn]);
    const float h = fmaf(ETA, s, X[n * BB + bb]);
    H1_t[bb * NN + n] = h;
    z_t[bb * NN + n] = fabsf(W[n] * h);
  }
}

// K3: partial c. grid 256 (64 b x 4 j-chunks of 256), block 256.
// Thread owns 4 n; scans its j-chunk via broadcast float4 LDS reads.
// Output layout c_part[b][q][n] so K4's merge is 4 stride-NN loads.
__global__ __launch_bounds__(256) void k_c(const float* __restrict__ z_t,
                                           float* __restrict__ c_part) {
  const int b = blockIdx.x >> 2;
  const int q = blockIdx.x & 3;
  const int t = threadIdx.x;
  __shared__ __align__(16) float4 z4[NN / 4];
  z4[t] = reinterpret_cast<const float4*>(z_t + b * NN)[t];
  __syncthreads();
  const float* zs = reinterpret_cast<const float*>(z4);
  const float zn0 = zs[t];
  const float zn1 = zs[t + 256];
  const float zn2 = zs[t + 512];
  const float zn3 = zs[t + 768];
  float c0 = 0.f, c1 = 0.f, c2 = 0.f, c3 = 0.f;
  const float4* zq = z4 + q * 64;
  #pragma unroll 4
  for (int i = 0; i < 64; ++i) {
    const float4 f = zq[i];
    c0 += (fabsf(zn0 - f.x) + fabsf(zn0 - f.y)) + (fabsf(zn0 - f.z) + fabsf(zn0 - f.w));
    c1 += (fabsf(zn1 - f.x) + fabsf(zn1 - f.y)) + (fabsf(zn1 - f.z) + fabsf(zn1 - f.w));
    c2 += (fabsf(zn2 - f.x) + fabsf(zn2 - f.y)) + (fabsf(zn2 - f.z) + fabsf(zn2 - f.w));
    c3 += (fabsf(zn3 - f.x) + fabsf(zn3 - f.y)) + (fabsf(zn3 - f.z) + fabsf(zn3 - f.w));
  }
  float* cp = c_part + (size_t)(b * 4 + q) * NN;
  cp[t] = c0;
  cp[t + 256] = c1;
  cp[t + 512] = c2;
  cp[t + 768] = c3;
}

// K4: softmax + mask + out. grid 64, block 512 (8 waves): mpart 32KB (half
// the LDS/barrier weight of the 16-wave version), lane owns 16 interleaved n;
// zc float2 reads (2-way, free), mpart scalar (conflict-free). Wave w
// handles s = w, w+8, ... (6-7 iters). Fixed-order merges -> deterministic.
__global__ __launch_bounds__(512) void k_sm(const float* __restrict__ z_t,
                                            const float* __restrict__ c_part,
                                            const float* __restrict__ H1_t,
                                            float* __restrict__ out) {
  const int b = blockIdx.x;
  const int t = threadIdx.x;  // 0..511
  const int l = t & 63;
  const int w = t >> 6;
  __shared__ __align__(16) float2 zc_s[NN];
  __shared__ float mpart[8][NN];

  const float* __restrict__ cb = c_part + (size_t)b * 4 * NN;
  {
    const int i0 = t, i1 = t + 512;
    const float cA = (cb[i0] + cb[i0 + NN]) + (cb[i0 + 2 * NN] + cb[i0 + 3 * NN]);
    const float cB = (cb[i1] + cb[i1 + NN]) + (cb[i1 + 2 * NN] + cb[i1 + 3 * NN]);
    zc_s[i0] = make_float2(z_t[b * NN + i0], cA);
    zc_s[i1] = make_float2(z_t[b * NN + i1], cB);
  }
  const float h0 = H1_t[b * NN + t];
  const float h1 = H1_t[b * NN + t + 512];
  __syncthreads();

  float zz[16], cc[16], mp[16];
  #pragma unroll
  for (int k = 0; k < 16; ++k) {
    const float2 v = zc_s[l + 64 * k];
    zz[k] = v.x;
    cc[k] = v.y;
    mp[k] = 0.f;
  }

  for (int s = w; s < SS; s += 8) {
    const float ks = (float)(NN + 1 - 2 * (s + 1));
    float lg[16];
    float mx = -INFINITY;
    #pragma unroll
    for (int k = 0; k < 16; ++k) {
      lg[k] = fmaf(ks, zz[k], -cc[k]);
      mx = fmaxf(mx, lg[k]);
    }
    #pragma unroll
    for (int off = 32; off > 0; off >>= 1)
      mx = fmaxf(mx, __shfl_xor(mx, off, 64));
    float sum = 0.f;
    #pragma unroll
    for (int k = 0; k < 16; ++k) {
      lg[k] = __expf(lg[k] - mx);
      sum += lg[k];
    }
    #pragma unroll
    for (int off = 32; off > 0; off >>= 1)
      sum += __shfl_xor(sum, off, 64);
    const float rs = 1.f / sum;
    #pragma unroll
    for (int k = 0; k < 16; ++k) mp[k] = fmaf(lg[k], rs, mp[k]);
  }
  #pragma unroll
  for (int k = 0; k < 16; ++k) mpart[w][l + 64 * k] = mp[k];
  __syncthreads();

  float m0 = 0.f, m1 = 0.f;
  #pragma unroll
  for (int u = 0; u < 8; ++u) {
    m0 += mpart[u][t];
    m1 += mpart[u][t + 512];
  }
  out[t * BB + b] = m0 * h0;
  out[(t + 512) * BB + b] = m1 * h1;
}

extern "C" void kernel_launch(void* const* d_in, const int* in_sizes, int n_in,
                              void* d_out, int out_size, void* d_ws, size_t ws_size,
                              hipStream_t stream) {
  const float* X = (const float*)d_in[0];  // (N,B)
  const float* Y = (const float*)d_in[1];  // (B,M)
  const float* A = (const float*)d_in[2];  // (M,N)
  const float* W = (const float*)d_in[3];  // (N,)
  float* out = (float*)d_out;              // (N,B)

  float* R_t = (float*)d_ws;               // (B,M) = 32768 f
  float* z_t = R_t + BB * MM;              // (B,N) = 65536 f
  float* H1_t = z_t + BB * NN;             // (B,N) = 65536 f
  float* c_part = H1_t + BB * NN;          // (B,4,N) = 262144 f

  k_r   <<<dim3(MM / 2), dim3(64, 8), 0, stream>>>(X, Y, A, R_t);
  k_h1z <<<dim3(256), dim3(64, 8), 0, stream>>>(X, A, R_t, W, H1_t, z_t);
  k_c   <<<dim3(BB * 4), dim3(256), 0, stream>>>(z_t, c_part);
  k_sm  <<<dim3(BB), dim3(512), 0, stream>>>(z_t, c_part, H1_t, out);
}

// Round 13
// 35.797 us; speedup vs baseline: 1.4259x; 1.0302x over previous
//
#include <hip/hip_runtime.h>
#include <math.h>

#define MM 512
#define NN 1024
#define BB 64
#define SS 50
#define ETA 0.1f

// K1: R_t[b][m] = Y[b,m] - sum_n A[m,n]*X[n,b]   (r8-proven)
// grid 256, block (64,8). Block owns 2 m-rows; wave w sums n-chunk w (128 n);
// 8-way LDS tree reduce; wave 0 writes float2 (m-pair) per batch.
__global__ __launch_bounds__(512) void k_r(const float* __restrict__ X,
                                           const float* __restrict__ Y,
                                           const float* __restrict__ A,
                                           float* __restrict__ R_t) {
  const int l = threadIdx.x;          // batch b
  const int w = threadIdx.y;          // n-chunk 0..7
  const int m0 = blockIdx.x * 2;
  __shared__ float part[8][2][BB];
  const float* __restrict__ Xp = X + w * 128 * BB + l;
  const float* __restrict__ A0 = A + (size_t)m0 * NN + w * 128;
  const float* __restrict__ A1 = A0 + NN;
  float r0a = 0.f, r0b = 0.f, r1a = 0.f, r1b = 0.f;
  #pragma unroll 8
  for (int i = 0; i < 128; i += 4) {
    const float x0 = Xp[(i + 0) * BB];
    const float x1 = Xp[(i + 1) * BB];
    const float x2 = Xp[(i + 2) * BB];
    const float x3 = Xp[(i + 3) * BB];
    const float4 a0 = *reinterpret_cast<const float4*>(A0 + i);
    const float4 a1 = *reinterpret_cast<const float4*>(A1 + i);
    r0a = fmaf(a0.x, x0, fmaf(a0.y, x1, r0a));
    r0b = fmaf(a0.z, x2, fmaf(a0.w, x3, r0b));
    r1a = fmaf(a1.x, x0, fmaf(a1.y, x1, r1a));
    r1b = fmaf(a1.z, x2, fmaf(a1.w, x3, r1b));
  }
  part[w][0][l] = r0a + r0b;
  part[w][1][l] = r1a + r1b;
  __syncthreads();
  if (w == 0) {
    const float s0 =
        ((part[0][0][l] + part[1][0][l]) + (part[2][0][l] + part[3][0][l])) +
        ((part[4][0][l] + part[5][0][l]) + (part[6][0][l] + part[7][0][l]));
    const float s1 =
        ((part[0][1][l] + part[1][1][l]) + (part[2][1][l] + part[3][1][l])) +
        ((part[4][1][l] + part[5][1][l]) + (part[6][1][l] + part[7][1][l]));
    const float2 y2 = *reinterpret_cast<const float2*>(Y + l * MM + m0);
    *reinterpret_cast<float2*>(R_t + l * MM + m0) =
        make_float2(y2.x - s0, y2.y - s1);
  }
}

// K2: H1_t[b,n] = X[n,b] + ETA*sum_m A[m,n]*R[m,b]; z_t[b,n] = |W[n]*H1|.
// grid 256 (8 nc x 32 bp), block (64,8). R staged in LDS; unroll 4.
__global__ __launch_bounds__(512) void k_h1z(const float* __restrict__ X,
                                             const float* __restrict__ A,
                                             const float* __restrict__ R_t,
                                             const float* __restrict__ W,
                                             float* __restrict__ H1_t,
                                             float* __restrict__ z_t) {
  const int l = threadIdx.x;
  const int w = threadIdx.y;          // 0..7
  const int nc = blockIdx.x & 7;
  const int bp = blockIdx.x >> 3;     // 0..31
  const int t5 = w * 64 + l;          // 0..511
  __shared__ __align__(16) float Rs[2][MM];
  __shared__ float p2[2][4][128];

  if (t5 < 256) {
    const int row = t5 >> 7;          // 0..1
    const int idx = t5 & 127;         // 0..127 float4s
    reinterpret_cast<float4*>(Rs[row])[idx] =
        reinterpret_cast<const float4*>(R_t + (size_t)(bp * 2 + row) * MM)[idx];
  }
  __syncthreads();

  const int b_l = w >> 2;             // 0..1
  const int mc = w & 3;               // m-chunk of 128
  const int n0 = nc * 128;
  const float2* __restrict__ A2 =
      reinterpret_cast<const float2*>(A) + (size_t)(mc * 128) * (NN / 2) + n0 / 2 + l;
  const float4* __restrict__ R4 =
      reinterpret_cast<const float4*>(Rs[b_l]) + mc * 32;
  float s0 = 0.f, s1 = 0.f, s2 = 0.f, s3 = 0.f;
  float u0 = 0.f, u1 = 0.f, u2 = 0.f, u3 = 0.f;
  #pragma unroll 4
  for (int i = 0; i < 128; i += 4) {
    const float4 r = R4[i >> 2];
    const float2 q0 = A2[(size_t)(i + 0) * (NN / 2)];
    const float2 q1 = A2[(size_t)(i + 1) * (NN / 2)];
    const float2 q2 = A2[(size_t)(i + 2) * (NN / 2)];
    const float2 q3 = A2[(size_t)(i + 3) * (NN / 2)];
    s0 = fmaf(q0.x, r.x, s0); u0 = fmaf(q0.y, r.x, u0);
    s1 = fmaf(q1.x, r.y, s1); u1 = fmaf(q1.y, r.y, u1);
    s2 = fmaf(q2.x, r.z, s2); u2 = fmaf(q2.y, r.z, u2);
    s3 = fmaf(q3.x, r.w, s3); u3 = fmaf(q3.y, r.w, u3);
  }
  p2[b_l][mc][l * 2 + 0] = (s0 + s1) + (s2 + s3);
  p2[b_l][mc][l * 2 + 1] = (u0 + u1) + (u2 + u3);
  __syncthreads();
  if (t5 < 256) {
    const int bl2 = t5 >> 7;
    const int nn = t5 & 127;
    const int bb = bp * 2 + bl2;
    const int n = n0 + nn;
    const float s = (p2[bl2][0][nn] + p2[bl2][1][nn]) +
                    (p2[bl2][2][nn] + p2[bl2][3][nn]);
    const float h = fmaf(ETA, s, X[n * BB + bb]);
    H1_t[bb * NN + n] = h;
    z_t[bb * NN + n] = fabsf(W[n] * h);
  }
}

// K3: partial c. grid 256 (64 b x 4 j-chunks of 256), block 256.  (r8-proven)
// Thread owns 4 n; scans its j-chunk via broadcast float4 LDS reads.
// Output layout c_part[b][q][n] so K4's merge is 4 stride-NN loads.
__global__ __launch_bounds__(256) void k_c(const float* __restrict__ z_t,
                                           float* __restrict__ c_part) {
  const int b = blockIdx.x >> 2;
  const int q = blockIdx.x & 3;
  const int t = threadIdx.x;
  __shared__ __align__(16) float4 z4[NN / 4];
  z4[t] = reinterpret_cast<const float4*>(z_t + b * NN)[t];
  __syncthreads();
  const float* zs = reinterpret_cast<const float*>(z4);
  const float zn0 = zs[t];
  const float zn1 = zs[t + 256];
  const float zn2 = zs[t + 512];
  const float zn3 = zs[t + 768];
  float c0 = 0.f, c1 = 0.f, c2 = 0.f, c3 = 0.f;
  const float4* zq = z4 + q * 64;
  #pragma unroll 4
  for (int i = 0; i < 64; ++i) {
    const float4 f = zq[i];
    c0 += (fabsf(zn0 - f.x) + fabsf(zn0 - f.y)) + (fabsf(zn0 - f.z) + fabsf(zn0 - f.w));
    c1 += (fabsf(zn1 - f.x) + fabsf(zn1 - f.y)) + (fabsf(zn1 - f.z) + fabsf(zn1 - f.w));
    c2 += (fabsf(zn2 - f.x) + fabsf(zn2 - f.y)) + (fabsf(zn2 - f.z) + fabsf(zn2 - f.w));
    c3 += (fabsf(zn3 - f.x) + fabsf(zn3 - f.y)) + (fabsf(zn3 - f.z) + fabsf(zn3 - f.w));
  }
  float* cp = c_part + (size_t)(b * 4 + q) * NN;
  cp[t] = c0;
  cp[t + 256] = c1;
  cp[t + 512] = c2;
  cp[t + 768] = c3;
}

// K4: softmax + mask + out. grid 64, block 1024 (16 waves; r8-proven).
// Lane owns 16 interleaved n; zc float2 reads (2-way, free), mpart scalar
// (conflict-free). Wave w handles s = w, w+16, w+32(, w+48). Fixed-order
// merges -> deterministic.
__global__ __launch_bounds__(1024) void k_sm(const float* __restrict__ z_t,
                                             const float* __restrict__ c_part,
                                             const float* __restrict__ H1_t,
                                             float* __restrict__ out) {
  const int b = blockIdx.x;
  const int t = threadIdx.x;
  __shared__ __align__(16) float2 zc_s[NN];
  __shared__ float mpart[16][NN];

  const float* __restrict__ cb = c_part + (size_t)b * 4 * NN;
  const float c = (cb[t] + cb[t + NN]) + (cb[t + 2 * NN] + cb[t + 3 * NN]);
  zc_s[t] = make_float2(z_t[b * NN + t], c);
  const float h = H1_t[b * NN + t];
  __syncthreads();

  const int w = t >> 6;
  const int lane = t & 63;
  float zz[16], cc[16], mp[16];
  #pragma unroll
  for (int k = 0; k < 16; ++k) {
    const float2 v = zc_s[lane + 64 * k];
    zz[k] = v.x;
    cc[k] = v.y;
    mp[k] = 0.f;
  }

  for (int s = w; s < SS; s += 16) {
    const float ks = (float)(NN + 1 - 2 * (s + 1));
    float lg[16];
    float mx = -INFINITY;
    #pragma unroll
    for (int k = 0; k < 16; ++k) {
      lg[k] = fmaf(ks, zz[k], -cc[k]);
      mx = fmaxf(mx, lg[k]);
    }
    #pragma unroll
    for (int off = 32; off > 0; off >>= 1)
      mx = fmaxf(mx, __shfl_xor(mx, off, 64));
    float sum = 0.f;
    #pragma unroll
    for (int k = 0; k < 16; ++k) {
      lg[k] = __expf(lg[k] - mx);
      sum += lg[k];
    }
    #pragma unroll
    for (int off = 32; off > 0; off >>= 1)
      sum += __shfl_xor(sum, off, 64);
    const float rs = 1.f / sum;
    #pragma unroll
    for (int k = 0; k < 16; ++k) mp[k] = fmaf(lg[k], rs, mp[k]);
  }
  #pragma unroll
  for (int k = 0; k < 16; ++k) mpart[w][lane + 64 * k] = mp[k];
  __syncthreads();

  float mask = 0.f;
  #pragma unroll
  for (int u = 0; u < 16; ++u) mask += mpart[u][t];
  out[t * BB + b] = mask * h;
}

extern "C" void kernel_launch(void* const* d_in, const int* in_sizes, int n_in,
                              void* d_out, int out_size, void* d_ws, size_t ws_size,
                              hipStream_t stream) {
  const float* X = (const float*)d_in[0];  // (N,B)
  const float* Y = (const float*)d_in[1];  // (B,M)
  const float* A = (const float*)d_in[2];  // (M,N)
  const float* W = (const float*)d_in[3];  // (N,)
  float* out = (float*)d_out;              // (N,B)

  float* R_t = (float*)d_ws;               // (B,M) = 32768 f
  float* z_t = R_t + BB * MM;              // (B,N) = 65536 f
  float* H1_t = z_t + BB * NN;             // (B,N) = 65536 f
  float* c_part = H1_t + BB * NN;          // (B,4,N) = 262144 f

  k_r   <<<dim3(MM / 2), dim3(64, 8), 0, stream>>>(X, Y, A, R_t);
  k_h1z <<<dim3(256), dim3(64, 8), 0, stream>>>(X, A, R_t, W, H1_t, z_t);
  k_c   <<<dim3(BB * 4), dim3(256), 0, stream>>>(z_t, c_part);
  k_sm  <<<dim3(BB), dim3(1024), 0, stream>>>(z_t, c_part, H1_t, out);
}